// Round 4
// baseline (17864.397 us; speedup 1.0000x reference)
//
#include <hip/hip_runtime.h>

// B=128, T=512, I=256, H=512, O=256. GRU (r,z,n), 2 layers sharing one hidden
// state (quirk), y_t = h @ W_out^T + b_out.
//
// Round 4: persistent kernel, plain launch, 64 blocks x 256 threads.
// Grid barrier hardened against cross-XCD L2 staleness: arrivals AND polls are
// atomic RMWs at agent scope (RMWs always execute at the device coherence
// point -> no stale-line livelock, which is the suspected round-3 hang).
// y(t-1) folded into phase A (waves 0-1 of each block take one y-tile each).
// h double-buffered; 2 barriers/step.

typedef short s16x8 __attribute__((ext_vector_type(8)));  // 8 bf16
typedef float f32x4 __attribute__((ext_vector_type(4)));
typedef unsigned short u16;

#define MFMA(a, b, c) __builtin_amdgcn_mfma_f32_16x16x32_bf16((a), (b), (c), 0, 0, 0)

static constexpr int NBLK = 64;

__device__ __forceinline__ u16 f2bf(float f) {
  unsigned u = __builtin_bit_cast(unsigned, f);
  u = u + 0x7fffu + ((u >> 16) & 1u);
  return (u16)(u >> 16);
}
__device__ __forceinline__ float sigm(float x) { return 1.f / (1.f + __expf(-x)); }
__device__ __forceinline__ float tanh_f(float x) { return 1.f - 2.f / (1.f + __expf(2.f * x)); }

// Grid barrier. Arrival: release fence + RMW(+1). Poll: RMW(+0) — executes at
// the device coherence point every time, cannot read a stale L2 copy. Exit:
// acquire fence (invalidate local caches so produced data is re-fetched).
__device__ __forceinline__ void gbar(unsigned* ctr) {
  __syncthreads();
  if (threadIdx.x == 0) {
    __builtin_amdgcn_fence(__ATOMIC_RELEASE, "agent");
    __hip_atomic_fetch_add(ctr, 1u, __ATOMIC_RELEASE, __HIP_MEMORY_SCOPE_AGENT);
    while (__hip_atomic_fetch_add(ctr, 0u, __ATOMIC_RELAXED, __HIP_MEMORY_SCOPE_AGENT)
           < (unsigned)NBLK) {
      __builtin_amdgcn_s_sleep(2);
    }
  }
  __syncthreads();
  __builtin_amdgcn_fence(__ATOMIC_ACQUIRE, "agent");
}

// ---------------- weight prep + barrier reset (once per call) ----------------
__global__ void prep_kernel(const float* __restrict__ W_ih0, const float* __restrict__ W_hh0,
                            const float* __restrict__ W_ih1, const float* __restrict__ W_hh1,
                            const float* __restrict__ W_out, const float* __restrict__ h0,
                            u16* __restrict__ WL0, u16* __restrict__ WL1,
                            u16* __restrict__ WOB, u16* __restrict__ HbB0,
                            float* __restrict__ HbF0, unsigned* __restrict__ bar) {
  const int n0 = 1536 * 768, n1 = 2048 * 512, n2 = 256 * 512, n3 = 128 * 512, n4 = 16384;
  const int total = n0 + n1 + n2 + n3 + n4;
  for (int i = blockIdx.x * blockDim.x + threadIdx.x; i < total; i += gridDim.x * blockDim.x) {
    if (i < n0) {
      int row = i / 768, c = i % 768;
      float v = (c < 256) ? W_ih0[row * 256 + c] : W_hh0[row * 512 + (c - 256)];
      WL0[i] = f2bf(v);
    } else if (i < n0 + n1) {
      int k2 = i - n0;
      int row = k2 / 512, k = k2 % 512;
      int strip = row >> 9, j = row & 511;
      float v;
      if (strip == 0)      v = W_ih1[j * 512 + k] + W_hh1[j * 512 + k];
      else if (strip == 1) v = W_ih1[(512 + j) * 512 + k] + W_hh1[(512 + j) * 512 + k];
      else if (strip == 2) v = W_ih1[(1024 + j) * 512 + k];
      else                 v = W_hh1[(1024 + j) * 512 + k];
      WL1[k2] = f2bf(v);
    } else if (i < n0 + n1 + n2) {
      int k2 = i - n0 - n1;
      WOB[k2] = f2bf(W_out[k2]);
    } else if (i < n0 + n1 + n2 + n3) {
      int k2 = i - n0 - n1 - n2;
      float v = h0[k2];
      HbF0[k2] = v;
      HbB0[k2] = f2bf(v);
    } else {
      bar[i - n0 - n1 - n2 - n3] = 0u;
    }
  }
}

// ---------------- persistent GRU kernel (64 blocks) ----------------
__global__ __launch_bounds__(256) void gru_persist(
    const float* __restrict__ x,
    const float* __restrict__ b_ih0, const float* __restrict__ b_hh0,
    const float* __restrict__ b_ih1, const float* __restrict__ b_hh1,
    const float* __restrict__ b_out,
    const u16* __restrict__ WL0, const u16* __restrict__ WL1, const u16* __restrict__ WOB,
    u16* __restrict__ HbB0, float* __restrict__ HbF0,
    u16* __restrict__ HbB1, float* __restrict__ HbF1,
    u16* __restrict__ hLB, float* __restrict__ hLF,
    float* __restrict__ Y, unsigned* __restrict__ bar) {
  const int blk = blockIdx.x;
  const int w = threadIdx.x >> 6, l = threadIdx.x & 63;
  const int l15 = l & 15, l4 = l >> 4;

  // ---- L0/L1 task mapping ----
  const int cg = blk & 31;                 // 16 hidden cols
  const int mt = (blk >> 5) * 4 + w;       // m-tile 0..7 (16 batch rows)
  const int brow = mt * 16 + l15;
  const int jg = cg * 16 + l15;
  const int b0 = mt * 16 + l4 * 4;
  const u16* wr  = WL0 + (size_t)jg * 768 + l4 * 8;
  const u16* wz  = WL0 + (size_t)(512 + jg) * 768 + l4 * 8;
  const u16* wn  = WL0 + (size_t)(1024 + jg) * 768 + l4 * 8;
  const u16* w10 = WL1 + (size_t)jg * 512 + l4 * 8;   // r (pre-summed)
  const u16* w11 = w10 + 512 * 512;                   // z (pre-summed)
  const u16* w12 = w10 + 1024 * 512;                  // i_n
  const u16* w13 = w10 + 1536 * 512;                  // h_n
  const float br0 = b_ih0[jg] + b_hh0[jg];
  const float bz0 = b_ih0[512 + jg] + b_hh0[512 + jg];
  const float bni0 = b_ih0[1024 + jg], bnh0 = b_hh0[1024 + jg];
  const float br1 = b_ih1[jg] + b_hh1[jg];
  const float bz1 = b_ih1[512 + jg] + b_hh1[512 + jg];
  const float bni1 = b_ih1[1024 + jg], bnh1 = b_hh1[1024 + jg];
  const float* xrow = x + (size_t)brow * 512 * 256 + l4 * 8;

  // ---- y-tile mapping: waves 0-1 of each block own one of 128 tiles ----
  const int yid = blk * 2 + w;             // 0..127 (valid when w < 2)
  const int ymt = yid & 7, ynt = yid >> 3;
  const int yo = ynt * 16 + l15;           // output col 0..255
  const float ybo = b_out[yo & 255];
  const u16* ywv = WOB + (size_t)(yo & 255) * 512 + l4 * 8;
  const int yarow = (ymt * 16 + l15) * 512 + l4 * 8;
  const int yb0 = ymt * 16 + l4 * 4;

  for (int t = 0; t < 512; ++t) {
    const u16* HbBc; const float* HbFc; u16* HbBn; float* HbFn;
    if (t & 1) { HbBc = HbB1; HbFc = HbF1; HbBn = HbB0; HbFn = HbF0; }
    else       { HbBc = HbB0; HbFc = HbF0; HbBn = HbB1; HbFn = HbF1; }

    // ---- y(t-1): reads HbBc (state after step t-1); phase B writes HbBn ----
    if (w < 2 && t > 0) {
      f32x4 acc = {0,0,0,0};
      const u16* ar = HbBc + yarow;
      #pragma unroll
      for (int kt = 0; kt < 16; ++kt)
        acc = MFMA(*(const s16x8*)(ar + kt * 32), *(const s16x8*)(ywv + kt * 32), acc);
      #pragma unroll
      for (int j = 0; j < 4; ++j)
        Y[((size_t)(yb0 + j) * 512 + (t - 1)) * 256 + yo] = acc[j] + ybo;
    }

    // ---- phase A: layer 0 gates ----
    f32x4 aR = {0,0,0,0}, aZ = {0,0,0,0}, aNI = {0,0,0,0}, aNH = {0,0,0,0};
    const float* xr = xrow + (size_t)t * 256;
    #pragma unroll
    for (int kt = 0; kt < 8; ++kt) {
      float4 u = *(const float4*)(xr + kt * 32);
      float4 v = *(const float4*)(xr + kt * 32 + 4);
      s16x8 a;
      a[0] = f2bf(u.x); a[1] = f2bf(u.y); a[2] = f2bf(u.z); a[3] = f2bf(u.w);
      a[4] = f2bf(v.x); a[5] = f2bf(v.y); a[6] = f2bf(v.z); a[7] = f2bf(v.w);
      aR  = MFMA(a, *(const s16x8*)(wr + kt * 32), aR);
      aZ  = MFMA(a, *(const s16x8*)(wz + kt * 32), aZ);
      aNI = MFMA(a, *(const s16x8*)(wn + kt * 32), aNI);
    }
    const u16* hr = HbBc + (size_t)brow * 512 + l4 * 8;
    #pragma unroll
    for (int kt = 0; kt < 16; ++kt) {
      s16x8 a = *(const s16x8*)(hr + kt * 32);
      aR  = MFMA(a, *(const s16x8*)(wr + (8 + kt) * 32), aR);
      aZ  = MFMA(a, *(const s16x8*)(wz + (8 + kt) * 32), aZ);
      aNH = MFMA(a, *(const s16x8*)(wn + (8 + kt) * 32), aNH);
    }
    #pragma unroll
    for (int j = 0; j < 4; ++j) {
      int bb = b0 + j;
      float r = sigm(aR[j] + br0);
      float z = sigm(aZ[j] + bz0);
      float n = tanh_f(aNI[j] + bni0 + r * (aNH[j] + bnh0));
      float h = (1.f - z) * n + z * HbFc[(size_t)bb * 512 + jg];
      hLF[(size_t)bb * 512 + jg] = h;
      hLB[(size_t)bb * 512 + jg] = f2bf(h);
    }
    gbar(bar + (size_t)(2 * t) * 16);

    // ---- phase B: layer 1 (input == hidden == h_l0, the quirk) ----
    f32x4 cR = {0,0,0,0}, cZ = {0,0,0,0}, cNI = {0,0,0,0}, cNH = {0,0,0,0};
    const u16* ar = hLB + (size_t)brow * 512 + l4 * 8;
    #pragma unroll
    for (int kt = 0; kt < 16; ++kt) {
      s16x8 a = *(const s16x8*)(ar + kt * 32);
      cR  = MFMA(a, *(const s16x8*)(w10 + kt * 32), cR);
      cZ  = MFMA(a, *(const s16x8*)(w11 + kt * 32), cZ);
      cNI = MFMA(a, *(const s16x8*)(w12 + kt * 32), cNI);
      cNH = MFMA(a, *(const s16x8*)(w13 + kt * 32), cNH);
    }
    #pragma unroll
    for (int j = 0; j < 4; ++j) {
      int bb = b0 + j;
      float r = sigm(cR[j] + br1);
      float z = sigm(cZ[j] + bz1);
      float n = tanh_f(cNI[j] + bni1 + r * (cNH[j] + bnh1));
      float h = (1.f - z) * n + z * hLF[(size_t)bb * 512 + jg];
      HbFn[(size_t)bb * 512 + jg] = h;
      HbBn[(size_t)bb * 512 + jg] = f2bf(h);
    }
    gbar(bar + (size_t)(2 * t + 1) * 16);
  }

  // ---- final y at t=511: state after step 511 is in buffer 0 ----
  if (w < 2) {
    f32x4 acc = {0,0,0,0};
    const u16* ar = HbB0 + yarow;
    #pragma unroll
    for (int kt = 0; kt < 16; ++kt)
      acc = MFMA(*(const s16x8*)(ar + kt * 32), *(const s16x8*)(ywv + kt * 32), acc);
    #pragma unroll
    for (int j = 0; j < 4; ++j)
      Y[((size_t)(yb0 + j) * 512 + 511) * 256 + yo] = acc[j] + ybo;
  }
}

extern "C" void kernel_launch(void* const* d_in, const int* in_sizes, int n_in,
                              void* d_out, int out_size, void* d_ws, size_t ws_size,
                              hipStream_t stream) {
  const float* x     = (const float*)d_in[0];
  const float* h0    = (const float*)d_in[1];
  const float* W_ih0 = (const float*)d_in[2];
  const float* W_hh0 = (const float*)d_in[3];
  const float* b_ih0 = (const float*)d_in[4];
  const float* b_hh0 = (const float*)d_in[5];
  const float* W_ih1 = (const float*)d_in[6];
  const float* W_hh1 = (const float*)d_in[7];
  const float* b_ih1 = (const float*)d_in[8];
  const float* b_hh1 = (const float*)d_in[9];
  const float* W_out = (const float*)d_in[10];
  const float* b_out = (const float*)d_in[11];
  float* Y = (float*)d_out;

  // ws carve (~5.7 MiB)
  u16* WL0  = (u16*)d_ws;             // 1536*768
  u16* WL1  = WL0 + 1536 * 768;       // 2048*512
  u16* WOB  = WL1 + 2048 * 512;       // 256*512
  u16* HbB0 = WOB + 256 * 512;        // 128*512
  u16* HbB1 = HbB0 + 128 * 512;
  u16* hLB  = HbB1 + 128 * 512;
  float* HbF0 = (float*)(hLB + 128 * 512);
  float* HbF1 = HbF0 + 128 * 512;
  float* hLF  = HbF1 + 128 * 512;
  unsigned* bar = (unsigned*)(hLF + 128 * 512);  // 1024 events * 16 uints

  prep_kernel<<<dim3(1024), dim3(256), 0, stream>>>(W_ih0, W_hh0, W_ih1, W_hh1,
                                                    W_out, h0, WL0, WL1, WOB,
                                                    HbB0, HbF0, bar);
  gru_persist<<<dim3(NBLK), dim3(256), 0, stream>>>(
      x, b_ih0, b_hh0, b_ih1, b_hh1, b_out, WL0, WL1, WOB,
      HbB0, HbF0, HbB1, HbF1, hLB, hLF, Y, bar);
}

// Round 5
// 14723.225 us; speedup vs baseline: 1.2133x; 1.2133x over previous
//
#include <hip/hip_runtime.h>

// B=128, T=512, I=256, H=512, O=256. GRU (r,z,n), 2 layers sharing one hidden
// state (quirk), y_t = h @ W_out^T + b_out.
//
// Round 5: fence-free persistent kernel. 64 blocks x 256 threads.
//  - f32 carries (h, h_l0) live in REGISTERS (same lane writes & reads them).
//  - cross-block bf16 h matrices (hLB, HbB0/1) move through MALL via inline-asm
//    sc0|sc1 loads/stores (device coherence point) -> no fences, weights stay
//    hot in L2 (round-4 fences/buffer_wbl2+inv were ~18us/step).
//  - barrier: vmcnt drain -> relaxed arrival RMW -> blk0 RMW-polls, then
//    sc-stores per-event "go"; others sc-load-poll "go". Events pre-zeroed.
//  - asm loads batched: issue 16 -> one s_waitcnt vmcnt(0) + sched_barrier(0).

typedef short s16x8 __attribute__((ext_vector_type(8)));  // 8 bf16
typedef float f32x4 __attribute__((ext_vector_type(4)));
typedef unsigned short u16;

#define MFMA(a, b, c) __builtin_amdgcn_mfma_f32_16x16x32_bf16((a), (b), (c), 0, 0, 0)

static constexpr int NBLK = 64;

__device__ __forceinline__ u16 f2bf(float f) {
  unsigned u = __builtin_bit_cast(unsigned, f);
  u = u + 0x7fffu + ((u >> 16) & 1u);
  return (u16)(u >> 16);
}
__device__ __forceinline__ float sigm(float x) { return 1.f / (1.f + __expf(-x)); }
__device__ __forceinline__ float tanh_f(float x) { return 1.f - 2.f / (1.f + __expf(2.f * x)); }

// ---- device-coherent (MALL-direct) access helpers ----
__device__ __forceinline__ s16x8 scload16(const u16* p) {
  s16x8 v;
  asm volatile("global_load_dwordx4 %0, %1, off sc0 sc1" : "=v"(v) : "v"(p));
  return v;  // NOT valid until a later s_waitcnt vmcnt(0)
}
__device__ __forceinline__ void scstore_u16(u16* p, u16 v) {
  unsigned vv = v;
  asm volatile("global_store_short %0, %1, off sc0 sc1" :: "v"(p), "v"(vv) : "memory");
}
__device__ __forceinline__ void scstore_f32(float* p, float v) {
  asm volatile("global_store_dword %0, %1, off sc0 sc1" :: "v"(p), "v"(v) : "memory");
}
#define VWAIT0()                                        \
  do {                                                  \
    asm volatile("s_waitcnt vmcnt(0)" ::: "memory");    \
    __builtin_amdgcn_sched_barrier(0);                  \
  } while (0)

// Grid barrier, fence-free. Event layout: ctr at +0, go word at +32 (128 B).
__device__ __forceinline__ void gbar(unsigned* ev, bool lead) {
  asm volatile("s_waitcnt vmcnt(0)" ::: "memory");  // drain sc-stores to MALL
  __syncthreads();
  if (threadIdx.x == 0) {
    __hip_atomic_fetch_add(ev, 1u, __ATOMIC_RELAXED, __HIP_MEMORY_SCOPE_AGENT);
    if (lead) {
      while (__hip_atomic_fetch_add(ev, 0u, __ATOMIC_RELAXED, __HIP_MEMORY_SCOPE_AGENT)
             < (unsigned)NBLK) {
        __builtin_amdgcn_s_sleep(2);
      }
      unsigned one = 1u;
      asm volatile("global_store_dword %0, %1, off sc0 sc1" :: "v"(ev + 32), "v"(one) : "memory");
    } else {
      unsigned g = 0;
      do {
        __builtin_amdgcn_s_sleep(2);
        asm volatile("global_load_dword %0, %1, off sc0 sc1\n\ts_waitcnt vmcnt(0)"
                     : "=v"(g) : "v"(ev + 32) : "memory");
      } while (g == 0);
    }
  }
  __syncthreads();
}

// ---------------- weight prep + barrier reset (once per call) ----------------
__global__ void prep_kernel(const float* __restrict__ W_ih0, const float* __restrict__ W_hh0,
                            const float* __restrict__ W_ih1, const float* __restrict__ W_hh1,
                            const float* __restrict__ W_out, const float* __restrict__ h0,
                            u16* __restrict__ WL0, u16* __restrict__ WL1,
                            u16* __restrict__ WOB, u16* __restrict__ HbB0,
                            unsigned* __restrict__ bar) {
  const int n0 = 1536 * 768, n1 = 2048 * 512, n2 = 256 * 512, n3 = 128 * 512, n4 = 65536;
  const int total = n0 + n1 + n2 + n3 + n4;
  for (int i = blockIdx.x * blockDim.x + threadIdx.x; i < total; i += gridDim.x * blockDim.x) {
    if (i < n0) {
      int row = i / 768, c = i % 768;
      float v = (c < 256) ? W_ih0[row * 256 + c] : W_hh0[row * 512 + (c - 256)];
      WL0[i] = f2bf(v);
    } else if (i < n0 + n1) {
      int k2 = i - n0;
      int row = k2 / 512, k = k2 % 512;
      int strip = row >> 9, j = row & 511;
      float v;
      if (strip == 0)      v = W_ih1[j * 512 + k] + W_hh1[j * 512 + k];
      else if (strip == 1) v = W_ih1[(512 + j) * 512 + k] + W_hh1[(512 + j) * 512 + k];
      else if (strip == 2) v = W_ih1[(1024 + j) * 512 + k];
      else                 v = W_hh1[(1024 + j) * 512 + k];
      WL1[k2] = f2bf(v);
    } else if (i < n0 + n1 + n2) {
      int k2 = i - n0 - n1;
      WOB[k2] = f2bf(W_out[k2]);
    } else if (i < n0 + n1 + n2 + n3) {
      int k2 = i - n0 - n1 - n2;
      HbB0[k2] = f2bf(h0[k2]);
    } else {
      bar[i - n0 - n1 - n2 - n3] = 0u;
    }
  }
}

// ---------------- persistent GRU kernel (64 blocks) ----------------
__global__ __launch_bounds__(256) void gru_persist(
    const float* __restrict__ x, const float* __restrict__ h0,
    const float* __restrict__ b_ih0, const float* __restrict__ b_hh0,
    const float* __restrict__ b_ih1, const float* __restrict__ b_hh1,
    const float* __restrict__ b_out,
    const u16* __restrict__ WL0, const u16* __restrict__ WL1, const u16* __restrict__ WOB,
    u16* __restrict__ HbB0, u16* __restrict__ HbB1, u16* __restrict__ hLB,
    float* __restrict__ Y, unsigned* __restrict__ bar) {
  const int blk = blockIdx.x;
  const bool lead = (blk == 0);
  const int w = threadIdx.x >> 6, l = threadIdx.x & 63;
  const int l15 = l & 15, l4 = l >> 4;

  // ---- L0/L1 task mapping ----
  const int cg = blk & 31;                 // 16 hidden cols
  const int mt = (blk >> 5) * 4 + w;       // m-tile 0..7 (16 batch rows)
  const int brow = mt * 16 + l15;
  const int jg = cg * 16 + l15;
  const int b0 = mt * 16 + l4 * 4;
  const u16* wr  = WL0 + (size_t)jg * 768 + l4 * 8;
  const u16* wz  = WL0 + (size_t)(512 + jg) * 768 + l4 * 8;
  const u16* wn  = WL0 + (size_t)(1024 + jg) * 768 + l4 * 8;
  const u16* w10 = WL1 + (size_t)jg * 512 + l4 * 8;   // r (pre-summed)
  const u16* w11 = w10 + 512 * 512;                   // z (pre-summed)
  const u16* w12 = w10 + 1024 * 512;                  // i_n
  const u16* w13 = w10 + 1536 * 512;                  // h_n
  const float br0 = b_ih0[jg] + b_hh0[jg];
  const float bz0 = b_ih0[512 + jg] + b_hh0[512 + jg];
  const float bni0 = b_ih0[1024 + jg], bnh0 = b_hh0[1024 + jg];
  const float br1 = b_ih1[jg] + b_hh1[jg];
  const float bz1 = b_ih1[512 + jg] + b_hh1[512 + jg];
  const float bni1 = b_ih1[1024 + jg], bnh1 = b_hh1[1024 + jg];
  const float* xrow = x + (size_t)brow * 512 * 256 + l4 * 8;

  // ---- register-resident f32 carries ----
  float hreg[4];   // h(t-1) at (b0+j, jg)  — same lane writes & reads
  #pragma unroll
  for (int j = 0; j < 4; ++j) hreg[j] = h0[(size_t)(b0 + j) * 512 + jg];
  float hl[4];     // h_l0 at (b0+j, jg) within a step

  // ---- y-tile mapping: waves 0-1 own one of 128 tiles ----
  const int yid = blk * 2 + w;             // valid when w < 2
  const int ymt = yid & 7, ynt = yid >> 3;
  const int yo = ynt * 16 + l15;
  const float ybo = b_out[yo];
  const u16* ywv = WOB + (size_t)yo * 512 + l4 * 8;
  const int yarow = (ymt * 16 + l15) * 512 + l4 * 8;
  const int yb0 = ymt * 16 + l4 * 4;

  for (int t = 0; t < 512; ++t) {
    u16* HbBc = (t & 1) ? HbB1 : HbB0;     // h(t-1), bf16
    u16* HbBn = (t & 1) ? HbB0 : HbB1;     // h(t) dest

    // ---- y(t-1): waves 0-1, reads HbBc via MALL ----
    if (w < 2 && t > 0) {
      s16x8 yb[16];
      const u16* ar = HbBc + yarow;
      #pragma unroll
      for (int kt = 0; kt < 16; ++kt) yb[kt] = scload16(ar + kt * 32);
      VWAIT0();
      f32x4 acc = {0, 0, 0, 0};
      #pragma unroll
      for (int kt = 0; kt < 16; ++kt)
        acc = MFMA(yb[kt], *(const s16x8*)(ywv + kt * 32), acc);
      #pragma unroll
      for (int j = 0; j < 4; ++j)
        scstore_f32(&Y[((size_t)(yb0 + j) * 512 + (t - 1)) * 256 + yo], acc[j] + ybo);
    }

    // ---- phase A: layer 0 ----
    f32x4 aR = {0,0,0,0}, aZ = {0,0,0,0}, aNI = {0,0,0,0}, aNH = {0,0,0,0};
    // x-part first (plain cached loads; no asm loads in flight yet)
    const float* xr = xrow + (size_t)t * 256;
    #pragma unroll
    for (int kt = 0; kt < 8; ++kt) {
      float4 u = *(const float4*)(xr + kt * 32);
      float4 v = *(const float4*)(xr + kt * 32 + 4);
      s16x8 a;
      a[0] = f2bf(u.x); a[1] = f2bf(u.y); a[2] = f2bf(u.z); a[3] = f2bf(u.w);
      a[4] = f2bf(v.x); a[5] = f2bf(v.y); a[6] = f2bf(v.z); a[7] = f2bf(v.w);
      aR  = MFMA(a, *(const s16x8*)(wr + kt * 32), aR);
      aZ  = MFMA(a, *(const s16x8*)(wz + kt * 32), aZ);
      aNI = MFMA(a, *(const s16x8*)(wn + kt * 32), aNI);
    }
    // h-part via MALL
    {
      s16x8 hb[16];
      const u16* hr = HbBc + (size_t)brow * 512 + l4 * 8;
      #pragma unroll
      for (int kt = 0; kt < 16; ++kt) hb[kt] = scload16(hr + kt * 32);
      VWAIT0();
      #pragma unroll
      for (int kt = 0; kt < 16; ++kt) {
        aR  = MFMA(hb[kt], *(const s16x8*)(wr + (8 + kt) * 32), aR);
        aZ  = MFMA(hb[kt], *(const s16x8*)(wz + (8 + kt) * 32), aZ);
        aNH = MFMA(hb[kt], *(const s16x8*)(wn + (8 + kt) * 32), aNH);
      }
    }
    #pragma unroll
    for (int j = 0; j < 4; ++j) {
      float r = sigm(aR[j] + br0);
      float z = sigm(aZ[j] + bz0);
      float n = tanh_f(aNI[j] + bni0 + r * (aNH[j] + bnh0));
      float h = (1.f - z) * n + z * hreg[j];
      hl[j] = h;
      scstore_u16(&hLB[(size_t)(b0 + j) * 512 + jg], f2bf(h));
    }
    gbar(bar + (size_t)(2 * t) * 64, lead);

    // ---- phase B: layer 1 (input == hidden == h_l0) ----
    f32x4 cR = {0,0,0,0}, cZ = {0,0,0,0}, cNI = {0,0,0,0}, cNH = {0,0,0,0};
    {
      s16x8 pb[16];
      const u16* ar = hLB + (size_t)brow * 512 + l4 * 8;
      #pragma unroll
      for (int kt = 0; kt < 16; ++kt) pb[kt] = scload16(ar + kt * 32);
      VWAIT0();
      #pragma unroll
      for (int kt = 0; kt < 16; ++kt) {
        cR  = MFMA(pb[kt], *(const s16x8*)(w10 + kt * 32), cR);
        cZ  = MFMA(pb[kt], *(const s16x8*)(w11 + kt * 32), cZ);
        cNI = MFMA(pb[kt], *(const s16x8*)(w12 + kt * 32), cNI);
        cNH = MFMA(pb[kt], *(const s16x8*)(w13 + kt * 32), cNH);
      }
    }
    #pragma unroll
    for (int j = 0; j < 4; ++j) {
      float r = sigm(cR[j] + br1);
      float z = sigm(cZ[j] + bz1);
      float n = tanh_f(cNI[j] + bni1 + r * (cNH[j] + bnh1));
      float h = (1.f - z) * n + z * hl[j];
      hreg[j] = h;
      scstore_u16(&HbBn[(size_t)(b0 + j) * 512 + jg], f2bf(h));
    }
    gbar(bar + (size_t)(2 * t + 1) * 64, lead);
  }

  // ---- final y (t = 511): state after step 511 is in buffer 0 ----
  if (w < 2) {
    s16x8 yb[16];
    const u16* ar = HbB0 + yarow;
    #pragma unroll
    for (int kt = 0; kt < 16; ++kt) yb[kt] = scload16(ar + kt * 32);
    VWAIT0();
    f32x4 acc = {0, 0, 0, 0};
    #pragma unroll
    for (int kt = 0; kt < 16; ++kt)
      acc = MFMA(yb[kt], *(const s16x8*)(ywv + kt * 32), acc);
    #pragma unroll
    for (int j = 0; j < 4; ++j)
      scstore_f32(&Y[((size_t)(yb0 + j) * 512 + 511) * 256 + yo], acc[j] + ybo);
  }
}

extern "C" void kernel_launch(void* const* d_in, const int* in_sizes, int n_in,
                              void* d_out, int out_size, void* d_ws, size_t ws_size,
                              hipStream_t stream) {
  const float* x     = (const float*)d_in[0];
  const float* h0    = (const float*)d_in[1];
  const float* W_ih0 = (const float*)d_in[2];
  const float* W_hh0 = (const float*)d_in[3];
  const float* b_ih0 = (const float*)d_in[4];
  const float* b_hh0 = (const float*)d_in[5];
  const float* W_ih1 = (const float*)d_in[6];
  const float* W_hh1 = (const float*)d_in[7];
  const float* b_ih1 = (const float*)d_in[8];
  const float* b_hh1 = (const float*)d_in[9];
  const float* W_out = (const float*)d_in[10];
  const float* b_out = (const float*)d_in[11];
  float* Y = (float*)d_out;

  // ws carve (~5.4 MiB)
  u16* WL0  = (u16*)d_ws;             // 1536*768
  u16* WL1  = WL0 + 1536 * 768;       // 2048*512
  u16* WOB  = WL1 + 2048 * 512;       // 256*512
  u16* HbB0 = WOB + 256 * 512;        // 128*512
  u16* HbB1 = HbB0 + 128 * 512;
  u16* hLB  = HbB1 + 128 * 512;
  unsigned* bar = (unsigned*)(hLB + 128 * 512);  // 1024 events * 64 u32 (256 B)

  prep_kernel<<<dim3(1024), dim3(256), 0, stream>>>(W_ih0, W_hh0, W_ih1, W_hh1,
                                                    W_out, h0, WL0, WL1, WOB,
                                                    HbB0, bar);
  gru_persist<<<dim3(NBLK), dim3(256), 0, stream>>>(
      x, h0, b_ih0, b_hh0, b_ih1, b_hh1, b_out, WL0, WL1, WOB,
      HbB0, HbB1, hLB, Y, bar);
}